// Round 14
// baseline (102.805 us; speedup 1.0000x reference)
//
#include <hip/hip_runtime.h>
#include <hip/hip_bf16.h>
#include <math.h>

namespace {

typedef short short8 __attribute__((ext_vector_type(8)));
typedef float floatx4 __attribute__((ext_vector_type(4)));
typedef unsigned int uint32;
typedef unsigned short u16;
typedef unsigned long long u64;

constexpr int S = 256, B = 32, D = 512, H = 512;
constexpr int BH = B * H;        // 16384
constexpr int M1 = S * B;        // 8192
constexpr int SBH = S * BH;      // 4194304 (== B*D*S)

// LDS tiles: rows of exactly 64 bf16 (128B), 16B slot XOR-swizzled by row&7.
__device__ __forceinline__ int swz(int row, int col8) {
  return row * 64 + (col8 ^ ((row & 7) << 3));
}

// Pack two f32 -> (bf16_lo | bf16_hi<<16) via v_cvt_pk_bf16_f32 (RNE).
__device__ __forceinline__ uint32 pkbf(float lo, float hi) {
  __hip_bfloat162 h = __float22bfloat162_rn(make_float2(lo, hi));
  uint32 r;
  __builtin_memcpy(&r, &h, 4);
  return r;
}

__device__ __forceinline__ float fast_sigmoid(float x) {
  float e = __expf(-x);
  return __builtin_amdgcn_rcpf(1.0f + e);
}
__device__ __forceinline__ float fast_tanh(float x) {
  float e = __expf(-2.0f * x);
  return fmaf(2.0f, __builtin_amdgcn_rcpf(1.0f + e), -1.0f);
}

// ---------------------------------------------------------------------------
// Proj GEMM (MFMA): pre[m][h] = sum_d x[m][d]*wm[h][d], dual-B, out float2.
// (unchanged from r11/r12)
// ---------------------------------------------------------------------------
__global__ __launch_bounds__(256) void proj_gemm(
    const float* __restrict__ x, const float* __restrict__ wmz,
    const float* __restrict__ wmf, float2* __restrict__ pzf) {
  __shared__ u16 As[128 * 64];
  __shared__ u16 Bzs[64 * 64];
  __shared__ u16 Bfs[64 * 64];
  const int tid = threadIdx.x;
  const int m0 = blockIdx.x * 128;
  const int n0 = blockIdx.y * 64;
  const int w = tid >> 6, l = tid & 63;
  const int lr = l & 15, lg = l >> 4;
  floatx4 accz[2][4], accf[2][4];
#pragma unroll
  for (int m = 0; m < 2; ++m)
#pragma unroll
    for (int n = 0; n < 4; ++n) {
      accz[m][n] = 0;
      accf[m][n] = 0;
    }
  const int sr = tid >> 3;         // 0..31
  const int sc = (tid & 7) * 8;    // 0..56
  for (int k0 = 0; k0 < D; k0 += 64) {
    __syncthreads();
#pragma unroll
    for (int p = 0; p < 4; ++p) {
      const int r = sr + 32 * p;
      const float* xp = &x[(size_t)(m0 + r) * D + k0 + sc];
      float4 a = *(const float4*)xp;
      float4 b = *(const float4*)(xp + 4);
      uint4 o;
      o.x = pkbf(a.x, a.y);
      o.y = pkbf(a.z, a.w);
      o.z = pkbf(b.x, b.y);
      o.w = pkbf(b.z, b.w);
      *(uint4*)&As[swz(r, sc)] = o;
    }
#pragma unroll
    for (int p = 0; p < 2; ++p) {
      const int r = sr + 32 * p;
      const float* zp = &wmz[(size_t)(n0 + r) * D + k0 + sc];
      float4 a = *(const float4*)zp;
      float4 b = *(const float4*)(zp + 4);
      uint4 o;
      o.x = pkbf(a.x, a.y);
      o.y = pkbf(a.z, a.w);
      o.z = pkbf(b.x, b.y);
      o.w = pkbf(b.z, b.w);
      *(uint4*)&Bzs[swz(r, sc)] = o;
      const float* fp = &wmf[(size_t)(n0 + r) * D + k0 + sc];
      float4 c = *(const float4*)fp;
      float4 d = *(const float4*)(fp + 4);
      uint4 q;
      q.x = pkbf(c.x, c.y);
      q.y = pkbf(c.z, c.w);
      q.z = pkbf(d.x, d.y);
      q.w = pkbf(d.z, d.w);
      *(uint4*)&Bfs[swz(r, sc)] = q;
    }
    __syncthreads();
    __builtin_amdgcn_s_setprio(1);
#pragma unroll
    for (int kk = 0; kk < 2; ++kk) {
      const int kb = kk * 32 + lg * 8;
      short8 a0 = *(const short8*)&As[swz(32 * w + lr, kb)];
      short8 a1 = *(const short8*)&As[swz(32 * w + 16 + lr, kb)];
#pragma unroll
      for (int n = 0; n < 4; ++n) {
        short8 bz = *(const short8*)&Bzs[swz(16 * n + lr, kb)];
        short8 bf = *(const short8*)&Bfs[swz(16 * n + lr, kb)];
        accz[0][n] = __builtin_amdgcn_mfma_f32_16x16x32_bf16(a0, bz, accz[0][n], 0, 0, 0);
        accz[1][n] = __builtin_amdgcn_mfma_f32_16x16x32_bf16(a1, bz, accz[1][n], 0, 0, 0);
        accf[0][n] = __builtin_amdgcn_mfma_f32_16x16x32_bf16(a0, bf, accf[0][n], 0, 0, 0);
        accf[1][n] = __builtin_amdgcn_mfma_f32_16x16x32_bf16(a1, bf, accf[1][n], 0, 0, 0);
      }
    }
    __builtin_amdgcn_s_setprio(0);
  }
#pragma unroll
  for (int m = 0; m < 2; ++m)
#pragma unroll
    for (int n = 0; n < 4; ++n)
#pragma unroll
      for (int j = 0; j < 4; ++j) {
        int row = m0 + 32 * w + 16 * m + lg * 4 + j;
        int col = n0 + 16 * n + lr;
        pzf[(size_t)row * H + col] = make_float2(accz[m][n][j], accf[m][n][j]);
      }
}

// ---------------------------------------------------------------------------
// Scan forward: unchanged except cells stores are nontemporal.
// ---------------------------------------------------------------------------
#define STEP_BODY(J)                                                       \
    const float z = fast_tanh(fmaf(wvz, cell, pzv));                       \
    const float f = fast_sigmoid(fmaf(wvf, cell, pfv));                    \
    const float zf = (1.0f - f) * (1.0f - z * z);                          \
    const float fz = (cell - z) * (1.0f - f) * f;                          \
    const float common = f + zf * wvz + fz * wvf;                          \
    wz = fmaf(common, wz, cell * zf);                                      \
    wf = fmaf(common, wf, cell * fz);                                      \
    bz = fmaf(common, bz, zf);                                             \
    bf = fmaf(common, bf, fz);                                             \
    cell = fmaf(f, cell - z, z);                                           \
    const size_t ti = (size_t)(t0 + (J)) * BH;                             \
    __builtin_nontemporal_store(cell, cp + ti);                            \
    pz[ti] = make_float2(__uint_as_float(pkbf(zf, fz)), common);

#define STEP_L(J, Q)                                                       \
  {                                                                        \
    const float pzv = Q.x + bsz, pfv = Q.y + bsf;                          \
    Q = pz[(size_t)(t0 + 16 + (J)) * BH];                                  \
    STEP_BODY(J)                                                           \
  }

#define STEP_N(J, Q)                                                       \
  {                                                                        \
    const float pzv = Q.x + bsz, pfv = Q.y + bsf;                          \
    STEP_BODY(J)                                                           \
  }

__global__ __launch_bounds__(64, 1) void scan_fwd(
    const float* __restrict__ hidden_prev, const float* __restrict__ wz0,
    const float* __restrict__ wf0, const float* __restrict__ bz0,
    const float* __restrict__ bf0, const float* __restrict__ wvz_,
    const float* __restrict__ wvf_, const float* __restrict__ bsz_,
    const float* __restrict__ bsf_, float2* pzf_,
    float* __restrict__ out_cells, float* __restrict__ out_newcell,
    float* __restrict__ out_wzn, float* __restrict__ out_wfn,
    float* __restrict__ out_bzn, float* __restrict__ out_bfn) {
  const int bh = blockIdx.x * 64 + threadIdx.x;
  const int h = bh & (H - 1);
  float cell = hidden_prev[bh];
  float wz = wz0[bh], wf = wf0[bh], bz = bz0[bh], bf = bf0[bh];
  const float wvz = wvz_[h], wvf = wvf_[h], bsz = bsz_[h], bsf = bsf_[h];
  float2* pz = pzf_ + bh;
  float* cp = out_cells + bh;

  float2 q0 = pz[(size_t)0 * BH], q1 = pz[(size_t)1 * BH];
  float2 q2 = pz[(size_t)2 * BH], q3 = pz[(size_t)3 * BH];
  float2 q4 = pz[(size_t)4 * BH], q5 = pz[(size_t)5 * BH];
  float2 q6 = pz[(size_t)6 * BH], q7 = pz[(size_t)7 * BH];
  float2 q8 = pz[(size_t)8 * BH], q9 = pz[(size_t)9 * BH];
  float2 q10 = pz[(size_t)10 * BH], q11 = pz[(size_t)11 * BH];
  float2 q12 = pz[(size_t)12 * BH], q13 = pz[(size_t)13 * BH];
  float2 q14 = pz[(size_t)14 * BH], q15 = pz[(size_t)15 * BH];

  for (int t0 = 0; t0 < S - 16; t0 += 16) {
    STEP_L(0, q0)  STEP_L(1, q1)  STEP_L(2, q2)  STEP_L(3, q3)
    STEP_L(4, q4)  STEP_L(5, q5)  STEP_L(6, q6)  STEP_L(7, q7)
    STEP_L(8, q8)  STEP_L(9, q9)  STEP_L(10, q10) STEP_L(11, q11)
    STEP_L(12, q12) STEP_L(13, q13) STEP_L(14, q14) STEP_L(15, q15)
  }
  {
    const int t0 = S - 16;
    STEP_N(0, q0)  STEP_N(1, q1)  STEP_N(2, q2)  STEP_N(3, q3)
    STEP_N(4, q4)  STEP_N(5, q5)  STEP_N(6, q6)  STEP_N(7, q7)
    STEP_N(8, q8)  STEP_N(9, q9)  STEP_N(10, q10) STEP_N(11, q11)
    STEP_N(12, q12) STEP_N(13, q13) STEP_N(14, q14) STEP_N(15, q15)
  }
  out_newcell[bh] = cell;
  out_wzn[bh] = wz;
  out_wfn[bh] = wf;
  out_bzn[bh] = bz;
  out_bfn[bh] = bf;
}

// ---------------------------------------------------------------------------
// Suffix products + AzT/AfT transpose + fused x->XT transpose (unchanged).
// ---------------------------------------------------------------------------
__global__ __launch_bounds__(1024) void suffix_kernel(
    const float2* __restrict__ pzfc, const float* __restrict__ x,
    u16* __restrict__ XT, u16* __restrict__ AzT, u16* __restrict__ AfT,
    float* __restrict__ P0_out) {
  __shared__ union {
    struct {
      float prods[16][65];
      uint32 tl[S * 65];
    } s;
    float xp[4][64][65];
  } u;
  const int tid = threadIdx.x;
  const int bh_l = tid & 63;
  const int c = tid >> 6;

  // ---- phase 0: xpose (4 tiles per block) ----
  {
    const int team = tid >> 8;              // 0..3
    const int tt = tid & 255;
    const int tile = blockIdx.x * 4 + team; // 0..1023
    const int b = tile >> 5;
    const int rem = tile & 31;
    const int d0 = (rem >> 2) * 64;
    const int s0 = (rem & 3) * 64;
    const int r = tt >> 4;                  // 0..15
    const int c4 = (tt & 15) * 4;           // 0..60
#pragma unroll
    for (int p = 0; p < 4; ++p) {
      const int rr = r + p * 16;
      float4 v = *(const float4*)&x[(size_t)(s0 + rr) * (B * D) +
                                    (size_t)b * D + d0 + c4];
      u.xp[team][c4 + 0][rr] = v.x;
      u.xp[team][c4 + 1][rr] = v.y;
      u.xp[team][c4 + 2][rr] = v.z;
      u.xp[team][c4 + 3][rr] = v.w;
    }
    __syncthreads();
#pragma unroll
    for (int p = 0; p < 4; ++p) {
      const int dr = r + p * 16;
      u64 o = (u64)pkbf(u.xp[team][dr][c4 + 0], u.xp[team][dr][c4 + 1]) |
              ((u64)pkbf(u.xp[team][dr][c4 + 2], u.xp[team][dr][c4 + 3]) << 32);
      *(u64*)&XT[((size_t)b * D + d0 + dr) * S + s0 + c4] = o;
    }
  }
  __syncthreads();

  // ---- phases 1-3: suffix products ----
  const int bh = blockIdx.x * 64 + bh_l;
  const float2* p = pzfc + bh;
  float2 v[16];
#pragma unroll
  for (int i = 0; i < 16; ++i) v[i] = p[(size_t)(c * 16 + i) * BH];
  float L = 1.0f;
#pragma unroll
  for (int i = 0; i < 16; ++i) L *= v[i].y;
  u.s.prods[c][bh_l] = L;
  __syncthreads();
  float run = 1.0f;
#pragma unroll
  for (int cc = 1; cc < 16; ++cc)
    if (cc > c) run *= u.s.prods[cc][bh_l];
#pragma unroll
  for (int i = 15; i >= 0; --i) {
    const int t = c * 16 + i;
    const uint32 w32 = __float_as_uint(v[i].x);
    const float zf = __uint_as_float((w32 & 0xffffu) << 16);
    const float fz = __uint_as_float(w32 & 0xffff0000u);
    u.s.tl[t * 65 + bh_l] = pkbf(zf * run, fz * run);
    run *= v[i].y;
  }
  if (c == 0) P0_out[bh] = run;
  __syncthreads();

  // ---- phase 4: transpose out, lane-rotated reads ----
  const size_t base = (size_t)blockIdx.x * 64 * S;
  const int rot = (bh_l >> 3) & 3;
#pragma unroll
  for (int it = 0; it < 4; ++it) {
    const int qi = it * 1024 + tid;          // 4096 quads
    const int r = qi >> 6;                   // chain row 0..63
    const int qt = (qi & 63) * 4;            // t 0..252
    uint32 a[4];
#pragma unroll
    for (int m = 0; m < 4; ++m) {
      const int k = (m + rot) & 3;
      a[k] = u.s.tl[(qt + k) * 65 + r];
    }
    u64 lo = (u64)(a[0] & 0xffffu) | ((u64)(a[1] & 0xffffu) << 16) |
             ((u64)(a[2] & 0xffffu) << 32) | ((u64)(a[3] & 0xffffu) << 48);
    u64 hi = (u64)(a[0] >> 16) | ((u64)(a[1] >> 16) << 16) |
             ((u64)(a[2] >> 16) << 32) | ((u64)(a[3] >> 16) << 48);
    *(u64*)&AzT[base + (size_t)r * S + qt] = lo;
    *(u64*)&AfT[base + (size_t)r * S + qt] = hi;
  }
}

// ---------------------------------------------------------------------------
// Out GEMM, round 13 (retry): r12 single-buffer pipeline + two locality
// fixes: (1) bijective XCD chunk-swizzle (T1) on a flat 2048 grid, d0
// decoded fastest so A-panel sharers are XCD-contiguous; (2) nontemporal
// Z0/F0 loads + Zn/Fn stores (use-once stream stops evicting L2 panels).
// ---------------------------------------------------------------------------
__global__ __launch_bounds__(256, 3) void out_gemm(
    const u16* __restrict__ AzT, const u16* __restrict__ AfT,
    const u16* __restrict__ XT, const float* __restrict__ P0,
    const float* __restrict__ Z0, const float* __restrict__ F0,
    float* __restrict__ Zn, float* __restrict__ Fn) {
  __shared__ u16 smem[(128 + 64) * 64];   // A 128x64 | X 64x64 (24KB)
  const int tid = threadIdx.x;
  // XCD chunk swizzle (nwg = 2048, divisible by 8 -> bijective).
  const int fid = blockIdx.x;
  const int L = (fid & 7) * 256 + (fid >> 3);
  const int d0 = (L & 7) * 64;             // fastest: A-panel sharers adjacent
  const int h0 = ((L >> 3) & 3) * 128;
  const int bz = L >> 5;
  const int b = bz >> 1;
  const u16* A = ((bz & 1) ? AfT : AzT) + (size_t)b * H * S;
  const float* C0 = (bz & 1) ? F0 : Z0;
  float* Cn = (bz & 1) ? Fn : Zn;
  const u16* Xb = XT + (size_t)b * D * S;
  const int w = tid >> 6, l = tid & 63;
  const int lr = l & 15, lg = l >> 4;
  floatx4 acc[2][4];
#pragma unroll
  for (int m = 0; m < 2; ++m)
#pragma unroll
    for (int n = 0; n < 4; ++n) acc[m][n] = 0;
  const int sr = tid >> 3;         // 0..31
  const int sc = (tid & 7) * 8;    // 0..56

  short8 rA[4], rX[2];

#define OG_LOAD(T0)                                                        \
  {                                                                        \
    _Pragma("unroll") for (int p = 0; p < 4; ++p) {                        \
      const int r = sr + 32 * p;                                           \
      rA[p] = *(const short8*)&A[(size_t)(h0 + r) * S + (T0) + sc];        \
    }                                                                      \
    _Pragma("unroll") for (int p = 0; p < 2; ++p) {                        \
      const int r = sr + 32 * p;                                           \
      rX[p] = *(const short8*)&Xb[(size_t)(d0 + r) * S + (T0) + sc];       \
    }                                                                      \
  }

#define OG_WRITE()                                                         \
  {                                                                        \
    u16* As_ = smem;                                                       \
    u16* Xs_ = smem + 128 * 64;                                            \
    _Pragma("unroll") for (int p = 0; p < 4; ++p) {                        \
      const int r = sr + 32 * p;                                           \
      *(short8*)&As_[swz(r, sc)] = rA[p];                                  \
    }                                                                      \
    _Pragma("unroll") for (int p = 0; p < 2; ++p) {                        \
      const int r = sr + 32 * p;                                           \
      *(short8*)&Xs_[swz(r, sc)] = rX[p];                                  \
    }                                                                      \
  }

#define OG_COMPUTE()                                                       \
  {                                                                        \
    const u16* As_ = smem;                                                 \
    const u16* Xs_ = smem + 128 * 64;                                      \
    __builtin_amdgcn_s_setprio(1);                                         \
    _Pragma("unroll") for (int kk = 0; kk < 2; ++kk) {                     \
      const int kb = kk * 32 + lg * 8;                                     \
      short8 a0 = *(const short8*)&As_[swz(32 * w + lr, kb)];              \
      short8 a1 = *(const short8*)&As_[swz(32 * w + 16 + lr, kb)];         \
      _Pragma("unroll") for (int n = 0; n < 4; ++n) {                      \
        short8 xf = *(const short8*)&Xs_[swz(16 * n + lr, kb)];            \
        acc[0][n] = __builtin_amdgcn_mfma_f32_16x16x32_bf16(a0, xf, acc[0][n], 0, 0, 0); \
        acc[1][n] = __builtin_amdgcn_mfma_f32_16x16x32_bf16(a1, xf, acc[1][n], 0, 0, 0); \
      }                                                                    \
    }                                                                      \
    __builtin_amdgcn_s_setprio(0);                                         \
  }

  OG_LOAD(0)
  OG_WRITE()
  __syncthreads();
  OG_LOAD(64)
  OG_COMPUTE()
  __syncthreads();
  OG_WRITE()
  __syncthreads();
  OG_LOAD(128)
  OG_COMPUTE()
  __syncthreads();
  OG_WRITE()
  __syncthreads();
  OG_LOAD(192)
  OG_COMPUTE()
  __syncthreads();
  OG_WRITE()
  __syncthreads();

  // Epilogue prefetch (nontemporal, ext-vector type) before the last compute.
  floatx4 c0v[8];
  float p0v[8];
#pragma unroll
  for (int half = 0; half < 2; ++half)
#pragma unroll
    for (int i = 0; i < 4; ++i) {
      const int id = i * 256 + tid;
      const int row = half * 64 + (id >> 4);   // 0..127
      const int c4 = (id & 15) * 4;            // 0..60
      const int h = h0 + row;
      p0v[half * 4 + i] = P0[b * H + h];
      c0v[half * 4 + i] = __builtin_nontemporal_load(
          (const floatx4*)&C0[((size_t)b * H + h) * D + d0 + c4]);
    }

  OG_COMPUTE()

  // ---- epilogue in two 64-row halves: acc -> LDS (f32) -> float4 IO ----
  float* eps = (float*)smem;               // 64 rows x pad 68 f32 = 17.4KB
#pragma unroll
  for (int half = 0; half < 2; ++half) {
    __syncthreads();                       // LDS reads (or prev half) done
    if ((w >> 1) == half) {
      const int lw = w & 1;
#pragma unroll
      for (int m = 0; m < 2; ++m)
#pragma unroll
        for (int n = 0; n < 4; ++n)
#pragma unroll
          for (int j = 0; j < 4; ++j) {
            const int row = 32 * lw + 16 * m + lg * 4 + j;   // 0..63
            eps[row * 68 + 16 * n + lr] = acc[m][n][j];
          }
    }
    __syncthreads();
#pragma unroll
    for (int i = 0; i < 4; ++i) {
      const int id = i * 256 + tid;
      const int row = id >> 4;             // 0..63
      const int c4 = (id & 15) * 4;        // 0..60
      const int h = h0 + half * 64 + row;
      const size_t gi = ((size_t)b * H + h) * D + d0 + c4;
      const floatx4 a = *(const floatx4*)&eps[row * 68 + c4];
      const int pi = half * 4 + i;
      floatx4 o;
      o[0] = fmaf(p0v[pi], c0v[pi][0], a[0]);
      o[1] = fmaf(p0v[pi], c0v[pi][1], a[1]);
      o[2] = fmaf(p0v[pi], c0v[pi][2], a[2]);
      o[3] = fmaf(p0v[pi], c0v[pi][3], a[3]);
      __builtin_nontemporal_store(o, (floatx4*)&Cn[gi]);
    }
  }
#undef OG_LOAD
#undef OG_WRITE
#undef OG_COMPUTE
}

}  // namespace

extern "C" void kernel_launch(void* const* d_in, const int* in_sizes, int n_in,
                              void* d_out, int out_size, void* d_ws,
                              size_t ws_size, hipStream_t stream) {
  const float* x = (const float*)d_in[0];
  const float* hidden_prev = (const float*)d_in[1];
  const float* Z_state = (const float*)d_in[2];
  const float* F_state = (const float*)d_in[3];
  const float* wz_state = (const float*)d_in[4];
  const float* wf_state = (const float*)d_in[5];
  const float* bz_state = (const float*)d_in[6];
  const float* bf_state = (const float*)d_in[7];
  const float* wm_z = (const float*)d_in[8];
  const float* wm_f = (const float*)d_in[9];
  const float* wv_z = (const float*)d_in[10];
  const float* wv_f = (const float*)d_in[11];
  const float* bias_z = (const float*)d_in[12];
  const float* bias_f = (const float*)d_in[13];

  // Workspace (~59 MB):
  float2* pzf = (float2*)d_ws;                 // [SBH]
  u16* AzT = (u16*)(pzf + SBH);                // [B*H*S] bf16
  u16* AfT = AzT + SBH;                        // [B*H*S] bf16
  u16* XT = AfT + SBH;                         // [B*D*S] bf16
  float* P0 = (float*)(XT + SBH);              // [BH]

  float* out = (float*)d_out;
  float* out_cells = out;                      // S*B*H
  float* out_newcell = out + SBH;              // B*H
  float* out_Zn = out_newcell + BH;            // B*H*D
  float* out_Fn = out_Zn + (size_t)BH * D;     // B*H*D
  float* out_wzn = out_Fn + (size_t)BH * D;    // B*H
  float* out_wfn = out_wzn + BH;
  float* out_bzn = out_wfn + BH;
  float* out_bfn = out_bzn + BH;

  proj_gemm<<<dim3(M1 / 128, H / 64), 256, 0, stream>>>(x, wm_z, wm_f, pzf);
  scan_fwd<<<BH / 64, 64, 0, stream>>>(
      hidden_prev, wz_state, wf_state, bz_state, bf_state, wv_z, wv_f, bias_z,
      bias_f, pzf, out_cells, out_newcell, out_wzn, out_wfn, out_bzn,
      out_bfn);
  suffix_kernel<<<BH / 64, 1024, 0, stream>>>(pzf, x, XT, AzT, AfT, P0);
  out_gemm<<<2048, 256, 0, stream>>>(
      AzT, AfT, XT, P0, Z_state, F_state, out_Zn, out_Fn);
}

// Round 15
// 97.090 us; speedup vs baseline: 1.0589x; 1.0589x over previous
//
#include <hip/hip_runtime.h>
#include <hip/hip_bf16.h>
#include <math.h>

namespace {

typedef short short8 __attribute__((ext_vector_type(8)));
typedef float floatx4 __attribute__((ext_vector_type(4)));
typedef unsigned int uint32;
typedef unsigned short u16;
typedef unsigned long long u64;

constexpr int S = 256, B = 32, D = 512, H = 512;
constexpr int BH = B * H;        // 16384
constexpr int M1 = S * B;        // 8192
constexpr int SBH = S * BH;      // 4194304 (== B*D*S)

// LDS tiles: rows of exactly 64 bf16 (128B), 16B slot XOR-swizzled by row&7.
__device__ __forceinline__ int swz(int row, int col8) {
  return row * 64 + (col8 ^ ((row & 7) << 3));
}

// Pack two f32 -> (bf16_lo | bf16_hi<<16) via v_cvt_pk_bf16_f32 (RNE).
__device__ __forceinline__ uint32 pkbf(float lo, float hi) {
  __hip_bfloat162 h = __float22bfloat162_rn(make_float2(lo, hi));
  uint32 r;
  __builtin_memcpy(&r, &h, 4);
  return r;
}

__device__ __forceinline__ float fast_sigmoid(float x) {
  float e = __expf(-x);
  return __builtin_amdgcn_rcpf(1.0f + e);
}
__device__ __forceinline__ float fast_tanh(float x) {
  float e = __expf(-2.0f * x);
  return fmaf(2.0f, __builtin_amdgcn_rcpf(1.0f + e), -1.0f);
}

// ---------------------------------------------------------------------------
// Proj GEMM (MFMA): pre[m][h] = sum_d x[m][d]*wm[h][d], dual-B, out float2.
// (unchanged)
// ---------------------------------------------------------------------------
__global__ __launch_bounds__(256) void proj_gemm(
    const float* __restrict__ x, const float* __restrict__ wmz,
    const float* __restrict__ wmf, float2* __restrict__ pzf) {
  __shared__ u16 As[128 * 64];
  __shared__ u16 Bzs[64 * 64];
  __shared__ u16 Bfs[64 * 64];
  const int tid = threadIdx.x;
  const int m0 = blockIdx.x * 128;
  const int n0 = blockIdx.y * 64;
  const int w = tid >> 6, l = tid & 63;
  const int lr = l & 15, lg = l >> 4;
  floatx4 accz[2][4], accf[2][4];
#pragma unroll
  for (int m = 0; m < 2; ++m)
#pragma unroll
    for (int n = 0; n < 4; ++n) {
      accz[m][n] = 0;
      accf[m][n] = 0;
    }
  const int sr = tid >> 3;         // 0..31
  const int sc = (tid & 7) * 8;    // 0..56
  for (int k0 = 0; k0 < D; k0 += 64) {
    __syncthreads();
#pragma unroll
    for (int p = 0; p < 4; ++p) {
      const int r = sr + 32 * p;
      const float* xp = &x[(size_t)(m0 + r) * D + k0 + sc];
      float4 a = *(const float4*)xp;
      float4 b = *(const float4*)(xp + 4);
      uint4 o;
      o.x = pkbf(a.x, a.y);
      o.y = pkbf(a.z, a.w);
      o.z = pkbf(b.x, b.y);
      o.w = pkbf(b.z, b.w);
      *(uint4*)&As[swz(r, sc)] = o;
    }
#pragma unroll
    for (int p = 0; p < 2; ++p) {
      const int r = sr + 32 * p;
      const float* zp = &wmz[(size_t)(n0 + r) * D + k0 + sc];
      float4 a = *(const float4*)zp;
      float4 b = *(const float4*)(zp + 4);
      uint4 o;
      o.x = pkbf(a.x, a.y);
      o.y = pkbf(a.z, a.w);
      o.z = pkbf(b.x, b.y);
      o.w = pkbf(b.z, b.w);
      *(uint4*)&Bzs[swz(r, sc)] = o;
      const float* fp = &wmf[(size_t)(n0 + r) * D + k0 + sc];
      float4 c = *(const float4*)fp;
      float4 d = *(const float4*)(fp + 4);
      uint4 q;
      q.x = pkbf(c.x, c.y);
      q.y = pkbf(c.z, c.w);
      q.z = pkbf(d.x, d.y);
      q.w = pkbf(d.z, d.w);
      *(uint4*)&Bfs[swz(r, sc)] = q;
    }
    __syncthreads();
    __builtin_amdgcn_s_setprio(1);
#pragma unroll
    for (int kk = 0; kk < 2; ++kk) {
      const int kb = kk * 32 + lg * 8;
      short8 a0 = *(const short8*)&As[swz(32 * w + lr, kb)];
      short8 a1 = *(const short8*)&As[swz(32 * w + 16 + lr, kb)];
#pragma unroll
      for (int n = 0; n < 4; ++n) {
        short8 bz = *(const short8*)&Bzs[swz(16 * n + lr, kb)];
        short8 bf = *(const short8*)&Bfs[swz(16 * n + lr, kb)];
        accz[0][n] = __builtin_amdgcn_mfma_f32_16x16x32_bf16(a0, bz, accz[0][n], 0, 0, 0);
        accz[1][n] = __builtin_amdgcn_mfma_f32_16x16x32_bf16(a1, bz, accz[1][n], 0, 0, 0);
        accf[0][n] = __builtin_amdgcn_mfma_f32_16x16x32_bf16(a0, bf, accf[0][n], 0, 0, 0);
        accf[1][n] = __builtin_amdgcn_mfma_f32_16x16x32_bf16(a1, bf, accf[1][n], 0, 0, 0);
      }
    }
    __builtin_amdgcn_s_setprio(0);
  }
#pragma unroll
  for (int m = 0; m < 2; ++m)
#pragma unroll
    for (int n = 0; n < 4; ++n)
#pragma unroll
      for (int j = 0; j < 4; ++j) {
        int row = m0 + 32 * w + 16 * m + lg * 4 + j;
        int col = n0 + 16 * n + lr;
        pzf[(size_t)row * H + col] = make_float2(accz[m][n][j], accf[m][n][j]);
      }
}

// ---------------------------------------------------------------------------
// Scan forward FUSED with x->XT transpose. 320 threads: wave 0 runs the
// serial scan for 64 chains (CU otherwise ~97% idle); waves 1-4 each
// transpose one 64x64 x-tile (4 tiles/block x 256 blocks = all 1024 tiles)
// using a private LDS slab + intra-wave s_waitcnt (no cross-wave barrier;
// the scan wave never syncs).
// ---------------------------------------------------------------------------
#define STEP_BODY(J)                                                       \
    const float z = fast_tanh(fmaf(wvz, cell, pzv));                       \
    const float f = fast_sigmoid(fmaf(wvf, cell, pfv));                    \
    const float zf = (1.0f - f) * (1.0f - z * z);                          \
    const float fz = (cell - z) * (1.0f - f) * f;                          \
    const float common = f + zf * wvz + fz * wvf;                          \
    wz = fmaf(common, wz, cell * zf);                                      \
    wf = fmaf(common, wf, cell * fz);                                      \
    bz = fmaf(common, bz, zf);                                             \
    bf = fmaf(common, bf, fz);                                             \
    cell = fmaf(f, cell - z, z);                                           \
    const size_t ti = (size_t)(t0 + (J)) * BH;                             \
    __builtin_nontemporal_store(cell, cp + ti);                            \
    pz[ti] = make_float2(__uint_as_float(pkbf(zf, fz)), common);

#define STEP_L(J, Q)                                                       \
  {                                                                        \
    const float pzv = Q.x + bsz, pfv = Q.y + bsf;                          \
    Q = pz[(size_t)(t0 + 16 + (J)) * BH];                                  \
    STEP_BODY(J)                                                           \
  }

#define STEP_N(J, Q)                                                       \
  {                                                                        \
    const float pzv = Q.x + bsz, pfv = Q.y + bsf;                          \
    STEP_BODY(J)                                                           \
  }

__global__ __launch_bounds__(320, 1) void scan_fwd(
    const float* __restrict__ hidden_prev, const float* __restrict__ wz0,
    const float* __restrict__ wf0, const float* __restrict__ bz0,
    const float* __restrict__ bf0, const float* __restrict__ wvz_,
    const float* __restrict__ wvf_, const float* __restrict__ bsz_,
    const float* __restrict__ bsf_, float2* pzf_,
    const float* __restrict__ x, u16* __restrict__ XT,
    float* __restrict__ out_cells, float* __restrict__ out_newcell,
    float* __restrict__ out_wzn, float* __restrict__ out_wfn,
    float* __restrict__ out_bzn, float* __restrict__ out_bfn) {
  __shared__ float xp[4][64][65];          // 66.6 KB, one slab per xpose wave
  const int tid = threadIdx.x;
  if (tid >= 64) {
    // ---------------- xpose waves (1..4) ----------------
    const int wv = (tid >> 6) - 1;          // 0..3
    const int l = tid & 63;
    const int tile = blockIdx.x * 4 + wv;   // 0..1023
    const int b = tile >> 5;
    const int rem = tile & 31;
    const int d0 = (rem >> 2) * 64;
    const int s0 = (rem & 3) * 64;
    float* lt = &xp[wv][0][0];
    const int rr = l >> 4;                  // 0..3
    const int cc = (l & 15) * 4;            // 0..60
#pragma unroll
    for (int p = 0; p < 16; ++p) {
      const int row = rr + p * 4;           // 0..63
      float4 v = *(const float4*)&x[(size_t)(s0 + row) * (B * D) +
                                    (size_t)b * D + d0 + cc];
      lt[(cc + 0) * 65 + row] = v.x;
      lt[(cc + 1) * 65 + row] = v.y;
      lt[(cc + 2) * 65 + row] = v.z;
      lt[(cc + 3) * 65 + row] = v.w;
    }
    asm volatile("s_waitcnt lgkmcnt(0)" ::: "memory");  // intra-wave order
#pragma unroll
    for (int p = 0; p < 16; ++p) {
      const int dr = rr + p * 4;            // 0..63 (d row within tile)
      u64 o = (u64)pkbf(lt[dr * 65 + cc + 0], lt[dr * 65 + cc + 1]) |
              ((u64)pkbf(lt[dr * 65 + cc + 2], lt[dr * 65 + cc + 3]) << 32);
      *(u64*)&XT[((size_t)b * D + d0 + dr) * S + s0 + cc] = o;
    }
    return;
  }
  // ---------------- scan wave (0) ----------------
  const int bh = blockIdx.x * 64 + tid;
  const int h = bh & (H - 1);
  float cell = hidden_prev[bh];
  float wz = wz0[bh], wf = wf0[bh], bz = bz0[bh], bf = bf0[bh];
  const float wvz = wvz_[h], wvf = wvf_[h], bsz = bsz_[h], bsf = bsf_[h];
  float2* pz = pzf_ + bh;
  float* cp = out_cells + bh;

  float2 q0 = pz[(size_t)0 * BH], q1 = pz[(size_t)1 * BH];
  float2 q2 = pz[(size_t)2 * BH], q3 = pz[(size_t)3 * BH];
  float2 q4 = pz[(size_t)4 * BH], q5 = pz[(size_t)5 * BH];
  float2 q6 = pz[(size_t)6 * BH], q7 = pz[(size_t)7 * BH];
  float2 q8 = pz[(size_t)8 * BH], q9 = pz[(size_t)9 * BH];
  float2 q10 = pz[(size_t)10 * BH], q11 = pz[(size_t)11 * BH];
  float2 q12 = pz[(size_t)12 * BH], q13 = pz[(size_t)13 * BH];
  float2 q14 = pz[(size_t)14 * BH], q15 = pz[(size_t)15 * BH];

  for (int t0 = 0; t0 < S - 16; t0 += 16) {
    STEP_L(0, q0)  STEP_L(1, q1)  STEP_L(2, q2)  STEP_L(3, q3)
    STEP_L(4, q4)  STEP_L(5, q5)  STEP_L(6, q6)  STEP_L(7, q7)
    STEP_L(8, q8)  STEP_L(9, q9)  STEP_L(10, q10) STEP_L(11, q11)
    STEP_L(12, q12) STEP_L(13, q13) STEP_L(14, q14) STEP_L(15, q15)
  }
  {
    const int t0 = S - 16;
    STEP_N(0, q0)  STEP_N(1, q1)  STEP_N(2, q2)  STEP_N(3, q3)
    STEP_N(4, q4)  STEP_N(5, q5)  STEP_N(6, q6)  STEP_N(7, q7)
    STEP_N(8, q8)  STEP_N(9, q9)  STEP_N(10, q10) STEP_N(11, q11)
    STEP_N(12, q12) STEP_N(13, q13) STEP_N(14, q14) STEP_N(15, q15)
  }
  out_newcell[bh] = cell;
  out_wzn[bh] = wz;
  out_wfn[bh] = wf;
  out_bzn[bh] = bz;
  out_bfn[bh] = bf;
}

// ---------------------------------------------------------------------------
// Suffix products + AzT/AfT transpose (xpose phase removed — now in scan).
// ---------------------------------------------------------------------------
__global__ __launch_bounds__(1024) void suffix_kernel(
    const float2* __restrict__ pzfc, u16* __restrict__ AzT,
    u16* __restrict__ AfT, float* __restrict__ P0_out) {
  __shared__ float prods[16][65];
  __shared__ uint32 tl[S * 65];
  const int tid = threadIdx.x;
  const int bh_l = tid & 63;
  const int c = tid >> 6;
  const int bh = blockIdx.x * 64 + bh_l;
  const float2* p = pzfc + bh;
  float2 v[16];
#pragma unroll
  for (int i = 0; i < 16; ++i) v[i] = p[(size_t)(c * 16 + i) * BH];
  float L = 1.0f;
#pragma unroll
  for (int i = 0; i < 16; ++i) L *= v[i].y;
  prods[c][bh_l] = L;
  __syncthreads();
  float run = 1.0f;
#pragma unroll
  for (int cc = 1; cc < 16; ++cc)
    if (cc > c) run *= prods[cc][bh_l];
#pragma unroll
  for (int i = 15; i >= 0; --i) {
    const int t = c * 16 + i;
    const uint32 w32 = __float_as_uint(v[i].x);
    const float zf = __uint_as_float((w32 & 0xffffu) << 16);
    const float fz = __uint_as_float(w32 & 0xffff0000u);
    tl[t * 65 + bh_l] = pkbf(zf * run, fz * run);
    run *= v[i].y;
  }
  if (c == 0) P0_out[bh] = run;
  __syncthreads();
  const size_t base = (size_t)blockIdx.x * 64 * S;
  const int rot = (bh_l >> 3) & 3;
#pragma unroll
  for (int it = 0; it < 4; ++it) {
    const int qi = it * 1024 + tid;          // 4096 quads
    const int r = qi >> 6;                   // chain row 0..63
    const int qt = (qi & 63) * 4;            // t 0..252
    uint32 a[4];
#pragma unroll
    for (int m = 0; m < 4; ++m) {
      const int k = (m + rot) & 3;
      a[k] = tl[(qt + k) * 65 + r];
    }
    u64 lo = (u64)(a[0] & 0xffffu) | ((u64)(a[1] & 0xffffu) << 16) |
             ((u64)(a[2] & 0xffffu) << 32) | ((u64)(a[3] & 0xffffu) << 48);
    u64 hi = (u64)(a[0] >> 16) | ((u64)(a[1] >> 16) << 16) |
             ((u64)(a[2] >> 16) << 32) | ((u64)(a[3] >> 16) << 48);
    *(u64*)&AzT[base + (size_t)r * S + qt] = lo;
    *(u64*)&AfT[base + (size_t)r * S + qt] = hi;
  }
}

// ---------------------------------------------------------------------------
// Out GEMM, round 15: BM=128, BN=128 (was 64), BK=64, (256,2).
//  - A-panel re-reads halved (4 d-blocks instead of 8): -67MB L2 traffic.
//  - 32 MFMA per K-step per kk-pair (2x MFMA:barrier ratio).
//  - grid 1024 at 2 blocks/CU = 2 exact launch rounds (no tail).
//  - single 32KB LDS buffer, same LOAD(t+1)/COMPUTE(t)/WRITE pipeline.
//  - epilogue in 4 quarter passes (32 rows x 132 pad f32 = 16.9KB <= 32KB),
//    all C IO float4 nontemporal.
// ---------------------------------------------------------------------------
__global__ __launch_bounds__(256, 2) void out_gemm(
    const u16* __restrict__ AzT, const u16* __restrict__ AfT,
    const u16* __restrict__ XT, const float* __restrict__ P0,
    const float* __restrict__ Z0, const float* __restrict__ F0,
    float* __restrict__ Zn, float* __restrict__ Fn) {
  __shared__ u16 smem[(128 + 128) * 64];   // A 128x64 | X 128x64 (32KB)
  const int tid = threadIdx.x;
  // XCD chunk swizzle (nwg = 1024, %8 == 0 -> bijective).
  const int fid = blockIdx.x;
  const int L = (fid & 7) * 128 + (fid >> 3);
  const int d0 = (L & 3) * 128;            // fastest: A-panel sharers adjacent
  const int h0 = ((L >> 2) & 3) * 128;
  const int bz = L >> 4;                   // 0..63
  const int b = bz >> 1;
  const u16* A = ((bz & 1) ? AfT : AzT) + (size_t)b * H * S;
  const float* C0 = (bz & 1) ? F0 : Z0;
  float* Cn = (bz & 1) ? Fn : Zn;
  const u16* Xb = XT + (size_t)b * D * S;
  const int w = tid >> 6, l = tid & 63;
  const int lr = l & 15, lg = l >> 4;
  floatx4 acc[2][8];
#pragma unroll
  for (int m = 0; m < 2; ++m)
#pragma unroll
    for (int n = 0; n < 8; ++n) acc[m][n] = 0;
  const int sr = tid >> 3;         // 0..31
  const int sc = (tid & 7) * 8;    // 0..56

  short8 rA[4], rX[4];

#define OG_LOAD(T0)                                                        \
  {                                                                        \
    _Pragma("unroll") for (int p = 0; p < 4; ++p) {                        \
      const int r = sr + 32 * p;                                           \
      rA[p] = *(const short8*)&A[(size_t)(h0 + r) * S + (T0) + sc];        \
      rX[p] = *(const short8*)&Xb[(size_t)(d0 + r) * S + (T0) + sc];       \
    }                                                                      \
  }

#define OG_WRITE()                                                         \
  {                                                                        \
    u16* As_ = smem;                                                       \
    u16* Xs_ = smem + 128 * 64;                                            \
    _Pragma("unroll") for (int p = 0; p < 4; ++p) {                        \
      const int r = sr + 32 * p;                                           \
      *(short8*)&As_[swz(r, sc)] = rA[p];                                  \
      *(short8*)&Xs_[swz(r, sc)] = rX[p];                                  \
    }                                                                      \
  }

#define OG_COMPUTE()                                                       \
  {                                                                        \
    const u16* As_ = smem;                                                 \
    const u16* Xs_ = smem + 128 * 64;                                      \
    __builtin_amdgcn_s_setprio(1);                                         \
    _Pragma("unroll") for (int kk = 0; kk < 2; ++kk) {                     \
      const int kb = kk * 32 + lg * 8;                                     \
      short8 a0 = *(const short8*)&As_[swz(32 * w + lr, kb)];              \
      short8 a1 = *(const short8*)&As_[swz(32 * w + 16 + lr, kb)];         \
      _Pragma("unroll") for (int n = 0; n < 8; ++n) {                      \
        short8 xf = *(const short8*)&Xs_[swz(16 * n + lr, kb)];            \
        acc[0][n] = __builtin_amdgcn_mfma_f32_16x16x32_bf16(a0, xf, acc[0][n], 0, 0, 0); \
        acc[1][n] = __builtin_amdgcn_mfma_f32_16x16x32_bf16(a1, xf, acc[1][n], 0, 0, 0); \
      }                                                                    \
    }                                                                      \
    __builtin_amdgcn_s_setprio(0);                                         \
  }

  OG_LOAD(0)
  OG_WRITE()
  __syncthreads();
  OG_LOAD(64)
  OG_COMPUTE()
  __syncthreads();
  OG_WRITE()
  __syncthreads();
  OG_LOAD(128)
  OG_COMPUTE()
  __syncthreads();
  OG_WRITE()
  __syncthreads();
  OG_LOAD(192)
  OG_COMPUTE()
  __syncthreads();
  OG_WRITE()
  __syncthreads();
  OG_COMPUTE()

  // ---- epilogue in 4 quarter passes: acc -> LDS (f32) -> float4 IO ----
  float* eps = (float*)smem;               // 32 rows x pad 132 f32 = 16.9KB
#pragma unroll
  for (int q = 0; q < 4; ++q) {
    __syncthreads();                       // LDS reads (or prev pass) done
    if (w == q) {
#pragma unroll
      for (int m = 0; m < 2; ++m)
#pragma unroll
        for (int n = 0; n < 8; ++n)
#pragma unroll
          for (int j = 0; j < 4; ++j) {
            const int row = 16 * m + lg * 4 + j;   // 0..31
            eps[row * 132 + 16 * n + lr] = acc[m][n][j];
          }
    }
    __syncthreads();
#pragma unroll
    for (int it = 0; it < 4; ++it) {
      const int id = it * 256 + tid;       // 0..1023
      const int row = id >> 5;             // 0..31
      const int c4 = (id & 31) * 4;        // 0..124
      const int h = h0 + q * 32 + row;
      const float p0 = P0[b * H + h];
      const size_t gi = ((size_t)b * H + h) * D + d0 + c4;
      const floatx4 a = *(const floatx4*)&eps[row * 132 + c4];
      const floatx4 c0 = __builtin_nontemporal_load((const floatx4*)&C0[gi]);
      floatx4 o;
      o[0] = fmaf(p0, c0[0], a[0]);
      o[1] = fmaf(p0, c0[1], a[1]);
      o[2] = fmaf(p0, c0[2], a[2]);
      o[3] = fmaf(p0, c0[3], a[3]);
      __builtin_nontemporal_store(o, (floatx4*)&Cn[gi]);
    }
  }
#undef OG_LOAD
#undef OG_WRITE
#undef OG_COMPUTE
}

}  // namespace

extern "C" void kernel_launch(void* const* d_in, const int* in_sizes, int n_in,
                              void* d_out, int out_size, void* d_ws,
                              size_t ws_size, hipStream_t stream) {
  const float* x = (const float*)d_in[0];
  const float* hidden_prev = (const float*)d_in[1];
  const float* Z_state = (const float*)d_in[2];
  const float* F_state = (const float*)d_in[3];
  const float* wz_state = (const float*)d_in[4];
  const float* wf_state = (const float*)d_in[5];
  const float* bz_state = (const float*)d_in[6];
  const float* bf_state = (const float*)d_in[7];
  const float* wm_z = (const float*)d_in[8];
  const float* wm_f = (const float*)d_in[9];
  const float* wv_z = (const float*)d_in[10];
  const float* wv_f = (const float*)d_in[11];
  const float* bias_z = (const float*)d_in[12];
  const float* bias_f = (const float*)d_in[13];

  // Workspace (~59 MB):
  float2* pzf = (float2*)d_ws;                 // [SBH]
  u16* AzT = (u16*)(pzf + SBH);                // [B*H*S] bf16
  u16* AfT = AzT + SBH;                        // [B*H*S] bf16
  u16* XT = AfT + SBH;                         // [B*D*S] bf16
  float* P0 = (float*)(XT + SBH);              // [BH]

  float* out = (float*)d_out;
  float* out_cells = out;                      // S*B*H
  float* out_newcell = out + SBH;              // B*H
  float* out_Zn = out_newcell + BH;            // B*H*D
  float* out_Fn = out_Zn + (size_t)BH * D;     // B*H*D
  float* out_wzn = out_Fn + (size_t)BH * D;    // B*H
  float* out_wfn = out_wzn + BH;
  float* out_bzn = out_wfn + BH;
  float* out_bfn = out_bzn + BH;

  proj_gemm<<<dim3(M1 / 128, H / 64), 256, 0, stream>>>(x, wm_z, wm_f, pzf);
  scan_fwd<<<BH / 64, 320, 0, stream>>>(
      hidden_prev, wz_state, wf_state, bz_state, bf_state, wv_z, wv_f, bias_z,
      bias_f, pzf, x, XT, out_cells, out_newcell, out_wzn, out_wfn, out_bzn,
      out_bfn);
  suffix_kernel<<<BH / 64, 1024, 0, stream>>>(pzf, AzT, AfT, P0);
  out_gemm<<<1024, 256, 0, stream>>>(
      AzT, AfT, XT, P0, Z_state, F_state, out_Zn, out_Fn);
}